// Round 5
// baseline (100.720 us; speedup 1.0000x reference)
//
#include <hip/hip_runtime.h>
#include <math.h>

#define CC 64
#define RR 4
#define HH 128
#define WW 128
#define BB 8
#define COUT 128
#define XCH 164   // xs channel stride in ushorts

typedef __attribute__((ext_vector_type(8))) short short8;
typedef __attribute__((ext_vector_type(4))) float f32x4;
typedef __attribute__((ext_vector_type(2))) float f32x2;

__device__ __forceinline__ unsigned short f2bf(float f) {
  unsigned u = __float_as_uint(f);
  u += 0x7fffu + ((u >> 16) & 1u);
  return (unsigned short)(u >> 16);
}
__device__ __forceinline__ float bf2f(unsigned short h) {
  return __uint_as_float(((unsigned)h) << 16);
}

// --- K0: pw -> bf16 (grid exactly COUT*RR*CC/256 blocks)
__global__ __launch_bounds__(256) void k_pre(const float* __restrict__ pw,
                                             unsigned short* __restrict__ pwb) {
  int i = blockIdx.x * 256 + threadIdx.x;
  pwb[i] = f2bf(pw[i]);
}

// --- K1: fully fused. tile: 2 rows x 32 cols; 2048 blocks; 4 blocks/CU target
__global__ __launch_bounds__(256, 4) void k_fused(const float* __restrict__ x,
                                                  const float* __restrict__ gw,
                                                  const float* __restrict__ gb,
                                                  const float* __restrict__ theta,
                                                  const float* __restrict__ rsu,
                                                  const float* __restrict__ rss,
                                                  const unsigned short* __restrict__ pwb,
                                                  const float* __restrict__ pb,
                                                  float* __restrict__ out) {
  __shared__ unsigned short xs[CC][XCH];            // bf16 x halo [c][row*40+col]
  __shared__ float mus[RR][4][40];                  // mu halo (cols 3..36 valid)
  __shared__ unsigned short alp[64][40];            // normalized bf16 alpha [px][s*4+r]
  __shared__ __align__(16) unsigned short aggs[16][264];  // bf16 agg per round
  float* rsum = (float*)&aggs[0][0];                // [4][64] alias (dead before aggs use)

  int tid = threadIdx.x;
  int raw = blockIdx.x;
  int bid = (raw & 7) * 256 + (raw >> 3);           // XCD swizzle (2048 % 8 == 0)
  int b = bid >> 8;
  int rem = bid & 255;
  int h0 = (rem >> 2) << 1;                         // 64 h-tiles of 2 rows
  int w0 = (rem & 3) << 5;                          // 4 w-tiles of 32 cols

  int lane = tid & 63;
  int wv = tid >> 6;
  int lr = lane & 15, lq = lane >> 4;
  int o0 = wv << 5;

  // ---- A-fragments + bias: issue global loads first (latency hides under A)
  short8 a0r[8], a1r[8];
  {
    const unsigned short* pA = pwb + ((o0 + lr) << 8) + (lq << 3);
    #pragma unroll
    for (int ks = 0; ks < 8; ++ks) {
      a0r[ks] = *(const short8*)(pA + (ks << 5));
      a1r[ks] = *(const short8*)(pA + 4096 + (ks << 5));
    }
  }
  float4 pbv0 = *(const float4*)&pb[o0 + (lq << 2)];
  float4 pbv1 = *(const float4*)&pb[o0 + 16 + (lq << 2)];

  // ---- phase A: stage x halo (pow2 mapping, full lane efficiency)
  #pragma unroll
  for (int k = 0; k < 8; ++k) {
    int i = (k << 8) + tid;            // [2:0]=c4 [8:3]=c [10:9]=row
    int c4 = i & 7, c = (i >> 3) & 63, row = (i >> 9) & 3;
    int gcol = w0 - 4 + (c4 << 2);
    int grow = h0 - 1 + row;
    float4 v = make_float4(0.f, 0.f, 0.f, 0.f);
    if ((unsigned)gcol < WW && (unsigned)grow < HH)
      v = *(const float4*)(x + (((size_t)b * CC + c) << 14) + (grow << 7) + gcol);
    ushort4 uv;
    uv.x = f2bf(v.x); uv.y = f2bf(v.y); uv.z = f2bf(v.z); uv.w = f2bf(v.w);
    *(ushort4*)&xs[c][row * 40 + (c4 << 2)] = uv;
  }
  #pragma unroll
  for (int k = 0; k < 2; ++k) {
    int i = (k << 8) + tid;            // [0]=slot [6:1]=c [8:7]=row
    int slot = i & 1, c = (i >> 1) & 63, row = (i >> 7) & 3;
    int gcol = w0 - 4 + 32 + (slot << 2);
    int grow = h0 - 1 + row;
    float4 v = make_float4(0.f, 0.f, 0.f, 0.f);
    if ((unsigned)gcol < WW && (unsigned)grow < HH)
      v = *(const float4*)(x + (((size_t)b * CC + c) << 14) + (grow << 7) + gcol);
    ushort4 uv;
    uv.x = f2bf(v.x); uv.y = f2bf(v.y); uv.z = f2bf(v.z); uv.w = f2bf(v.w);
    *(ushort4*)&xs[c][row * 40 + 32 + (slot << 2)] = uv;
  }
  __syncthreads();

  // ---- phase Mu: softmax gate for the 4x34 halo
  if (tid < 136) {
    int y = tid / 34, cxo = tid % 34;
    int cx = 3 + cxo;
    int grow = h0 - 1 + y, gcol = w0 - 1 + cxo;
    float lg0 = gb[0], lg1 = gb[1], lg2 = gb[2], lg3 = gb[3];
    #pragma unroll 8
    for (int c = 0; c < CC; ++c) {
      float xv = bf2f(xs[c][y * 40 + cx]);
      lg0 = fmaf(xv, gw[c], lg0);
      lg1 = fmaf(xv, gw[64 + c], lg1);
      lg2 = fmaf(xv, gw[128 + c], lg2);
      lg3 = fmaf(xv, gw[192 + c], lg3);
    }
    float m = fmaxf(fmaxf(lg0, lg1), fmaxf(lg2, lg3));
    float e0 = expf(lg0 - m), e1 = expf(lg1 - m);
    float e2 = expf(lg2 - m), e3 = expf(lg3 - m);
    float inv = 1.0f / (e0 + e1 + e2 + e3);
    if (!((unsigned)grow < HH && (unsigned)gcol < WW)) inv = 0.0f;  // zero-pad mu
    mus[0][y][cx] = e0 * inv;
    mus[1][y][cx] = e1 * inv;
    mus[2][y][cx] = e2 * inv;
    mus[3][y][cx] = e3 * inv;
  }
  __syncthreads();

  // ---- phase B: raw alpha per (px, r) with in-register kern; write rsum
  float a9[9];
  {
    int t = tid & 63, r = tid >> 6;          // r wave-uniform
    float th = theta[r];
    float ct = cosf(th), st = sinf(th);
    float su = log1pf(expf(rsu[r])) + 1e-4f;
    float sv = log1pf(expf(rss[r])) + 1e-4f;
    float isu = 1.0f / (su * su), isv = 1.0f / (sv * sv);
    int prow = t >> 5, pcol = t & 31;
    float mc = mus[r][prow + 1][pcol + 4];
    float sum = 0.f;
    #pragma unroll
    for (int s = 0; s < 9; ++s) {
      float dy = (float)(s / 3 - 1), dx = (float)(s % 3 - 1);
      float pu = ct * dx + st * dy;
      float ps = -st * dx + ct * dy;
      float kern = expf(-pu * pu * isu - ps * ps * isv);
      float av = mc * mus[r][prow + s / 3][pcol + 3 + s % 3] * kern;
      a9[s] = av;
      sum += av;
    }
    rsum[(r << 6) + t] = sum;
  }
  __syncthreads();

  // ---- fold: normalize alpha, store bf16 [px][s*4+r]
  {
    int t = tid & 63, r = tid >> 6;
    float tot = rsum[t] + rsum[64 + t] + rsum[128 + t] + rsum[192 + t];
    float inv = 1.0f / fmaxf(tot, 1e-8f);
    #pragma unroll
    for (int s = 0; s < 9; ++s)
      alp[t][(s << 2) + r] = f2bf(a9[s] * inv);
  }
  __syncthreads();

  // ---- rounds: 4 x (C: 16-px agg -> D: MFMA GEMM)
  #pragma unroll
  for (int rd = 0; rd < 4; ++rd) {
    // phase C
    {
      int t16 = tid & 15, cg = tid >> 4, c0 = cg << 2;
      int px = (rd << 4) + t16;
      int prow2 = px >> 5, pc = px & 31;
      f32x2 cacc[4][2];
      #pragma unroll
      for (int r = 0; r < 4; ++r) {
        cacc[r][0] = (f32x2){0.f, 0.f};
        cacc[r][1] = (f32x2){0.f, 0.f};
      }
      const unsigned short* arow = &alp[px][0];
      #pragma unroll
      for (int s = 0; s < 9; ++s) {
        uint2 ad = *(const uint2*)(arow + (s << 2));
        float af0 = __uint_as_float(ad.x << 16);
        float af1 = __uint_as_float(ad.x & 0xffff0000u);
        float af2 = __uint_as_float(ad.y << 16);
        float af3 = __uint_as_float(ad.y & 0xffff0000u);
        int xo = (prow2 + s / 3) * 40 + pc + 3 + s % 3;
        f32x2 xv0, xv1;
        xv0[0] = bf2f(xs[c0][xo]);     xv0[1] = bf2f(xs[c0 + 1][xo]);
        xv1[0] = bf2f(xs[c0 + 2][xo]); xv1[1] = bf2f(xs[c0 + 3][xo]);
        f32x2 A0 = {af0, af0}, A1 = {af1, af1}, A2 = {af2, af2}, A3 = {af3, af3};
        cacc[0][0] += A0 * xv0; cacc[0][1] += A0 * xv1;
        cacc[1][0] += A1 * xv0; cacc[1][1] += A1 * xv1;
        cacc[2][0] += A2 * xv0; cacc[2][1] += A2 * xv1;
        cacc[3][0] += A3 * xv0; cacc[3][1] += A3 * xv1;
      }
      #pragma unroll
      for (int r = 0; r < 4; ++r) {
        ushort4 wvv;
        wvv.x = f2bf(cacc[r][0][0]); wvv.y = f2bf(cacc[r][0][1]);
        wvv.z = f2bf(cacc[r][1][0]); wvv.w = f2bf(cacc[r][1][1]);
        *(ushort4*)&aggs[t16][(r << 6) + c0] = wvv;
      }
    }
    __syncthreads();

    // phase D: out[128][16px] = pwb @ aggs^T via mfma 16x16x32 bf16
    {
      f32x4 dacc0 = (f32x4){0.f, 0.f, 0.f, 0.f};
      f32x4 dacc1 = (f32x4){0.f, 0.f, 0.f, 0.f};
      #pragma unroll
      for (int ks = 0; ks < 8; ++ks) {
        short8 b0 = *(const short8*)&aggs[lr][(ks << 5) + (lq << 3)];
        dacc0 = __builtin_amdgcn_mfma_f32_16x16x32_bf16(a0r[ks], b0, dacc0, 0, 0, 0);
        dacc1 = __builtin_amdgcn_mfma_f32_16x16x32_bf16(a1r[ks], b0, dacc1, 0, 0, 0);
      }
      int orow = h0 + (rd >> 1);
      int oc = w0 + ((rd & 1) << 4) + lr;
      #pragma unroll
      for (int q = 0; q < 4; ++q) {
        int o = o0 + (lq << 2) + q;
        out[(((size_t)b * COUT + o) << 14) + (orow << 7) + oc] = dacc0[q] + pbv0[q];
        out[(((size_t)b * COUT + o + 16) << 14) + (orow << 7) + oc] = dacc1[q] + pbv1[q];
      }
    }
    if (rd < 3) __syncthreads();
  }
}

extern "C" void kernel_launch(void* const* d_in, const int* in_sizes, int n_in,
                              void* d_out, int out_size, void* d_ws, size_t ws_size,
                              hipStream_t stream) {
  const float* x     = (const float*)d_in[0];
  const float* gw    = (const float*)d_in[1];
  const float* gb    = (const float*)d_in[2];
  const float* theta = (const float*)d_in[3];
  const float* rsu   = (const float*)d_in[4];
  const float* rss   = (const float*)d_in[5];
  const float* pw    = (const float*)d_in[6];
  const float* pb    = (const float*)d_in[7];
  float* outp = (float*)d_out;

  unsigned short* pwb = (unsigned short*)d_ws;   // 32768 bf16 = 64KB

  k_pre<<<(COUT * RR * CC) / 256, 256, 0, stream>>>(pw, pwb);
  k_fused<<<BB * (HH / 2) * (WW / 32), 256, 0, stream>>>(x, gw, gb, theta, rsu, rss,
                                                         pwb, pb, outp);
}

// Round 6
// 76.837 us; speedup vs baseline: 1.3108x; 1.3108x over previous
//
#include <hip/hip_runtime.h>
#include <math.h>

#define CC 64
#define RR 4
#define HH 128
#define WW 128
#define BB 8
#define COUT 128
#define XCH 164   // xs channel stride in ushorts

typedef __attribute__((ext_vector_type(8))) short short8;
typedef __attribute__((ext_vector_type(4))) float f32x4;
typedef __attribute__((ext_vector_type(2))) float f32x2;

__device__ __forceinline__ unsigned short f2bf(float f) {
  unsigned u = __float_as_uint(f);
  u += 0x7fffu + ((u >> 16) & 1u);
  return (unsigned short)(u >> 16);
}
__device__ __forceinline__ float bf2f(unsigned short h) {
  return __uint_as_float(((unsigned)h) << 16);
}

// --- K0: pw -> bf16
__global__ __launch_bounds__(256) void k_pre(const float* __restrict__ pw,
                                             unsigned short* __restrict__ pwb) {
  int i = blockIdx.x * 256 + threadIdx.x;
  pwb[i] = f2bf(pw[i]);
}

// --- K1: fully fused. tile: 2 rows x 32 cols; 2048 blocks; 4 blocks/CU
__global__ __launch_bounds__(256, 4) void k_fused(const float* __restrict__ x,
                                                  const float* __restrict__ gw,
                                                  const float* __restrict__ gb,
                                                  const float* __restrict__ theta,
                                                  const float* __restrict__ rsu,
                                                  const float* __restrict__ rss,
                                                  const unsigned short* __restrict__ pwb,
                                                  const float* __restrict__ pb,
                                                  float* __restrict__ out) {
  __shared__ unsigned short xs[CC][XCH];            // bf16 x halo [c][row*40+col]
  __shared__ float mus[RR][4][40];                  // mu halo (cols 3..36 valid)
  __shared__ unsigned short alp[64][40];            // normalized bf16 alpha [px][s*4+r]
  __shared__ __align__(16) unsigned short aggs[16][264];  // bf16 agg per round
  float* rsum = (float*)&aggs[0][0];                // [4][64] alias (dead before aggs use)

  int tid = threadIdx.x;
  int raw = blockIdx.x;
  int bid = (raw & 7) * 256 + (raw >> 3);           // XCD swizzle (2048 % 8 == 0)
  int b = bid >> 8;
  int rem = bid & 255;
  int h0 = (rem >> 2) << 1;                         // 64 h-tiles of 2 rows
  int w0 = (rem & 3) << 5;                          // 4 w-tiles of 32 cols

  int lane = tid & 63;
  int wv = tid >> 6;
  int lr = lane & 15, lq = lane >> 4;
  int o0 = wv << 5;

  // ---- A-fragments + bias: issue global loads first (latency hides under A)
  short8 a0r[8], a1r[8];
  {
    const unsigned short* pA = pwb + ((o0 + lr) << 8) + (lq << 3);
    #pragma unroll
    for (int ks = 0; ks < 8; ++ks) {
      a0r[ks] = *(const short8*)(pA + (ks << 5));
      a1r[ks] = *(const short8*)(pA + 4096 + (ks << 5));
    }
  }
  float4 pbv0 = *(const float4*)&pb[o0 + (lq << 2)];
  float4 pbv1 = *(const float4*)&pb[o0 + 16 + (lq << 2)];

  // ---- phase A: stage x halo (pow2 mapping, full lane efficiency)
  #pragma unroll
  for (int k = 0; k < 8; ++k) {
    int i = (k << 8) + tid;            // [2:0]=c4 [8:3]=c [10:9]=row
    int c4 = i & 7, c = (i >> 3) & 63, row = (i >> 9) & 3;
    int gcol = w0 - 4 + (c4 << 2);
    int grow = h0 - 1 + row;
    float4 v = make_float4(0.f, 0.f, 0.f, 0.f);
    if ((unsigned)gcol < WW && (unsigned)grow < HH)
      v = *(const float4*)(x + (((size_t)b * CC + c) << 14) + (grow << 7) + gcol);
    ushort4 uv;
    uv.x = f2bf(v.x); uv.y = f2bf(v.y); uv.z = f2bf(v.z); uv.w = f2bf(v.w);
    *(ushort4*)&xs[c][row * 40 + (c4 << 2)] = uv;
  }
  #pragma unroll
  for (int k = 0; k < 2; ++k) {
    int i = (k << 8) + tid;            // [0]=slot [6:1]=c [8:7]=row
    int slot = i & 1, c = (i >> 1) & 63, row = (i >> 7) & 3;
    int gcol = w0 - 4 + 32 + (slot << 2);
    int grow = h0 - 1 + row;
    float4 v = make_float4(0.f, 0.f, 0.f, 0.f);
    if ((unsigned)gcol < WW && (unsigned)grow < HH)
      v = *(const float4*)(x + (((size_t)b * CC + c) << 14) + (grow << 7) + gcol);
    ushort4 uv;
    uv.x = f2bf(v.x); uv.y = f2bf(v.y); uv.z = f2bf(v.z); uv.w = f2bf(v.w);
    *(ushort4*)&xs[c][row * 40 + 32 + (slot << 2)] = uv;
  }
  __syncthreads();

  // ---- phase Mu: softmax gate for the 4x34 halo
  if (tid < 136) {
    int y = tid / 34, cxo = tid % 34;
    int cx = 3 + cxo;
    int grow = h0 - 1 + y, gcol = w0 - 1 + cxo;
    float lg0 = gb[0], lg1 = gb[1], lg2 = gb[2], lg3 = gb[3];
    #pragma unroll 8
    for (int c = 0; c < CC; ++c) {
      float xv = bf2f(xs[c][y * 40 + cx]);
      lg0 = fmaf(xv, gw[c], lg0);
      lg1 = fmaf(xv, gw[64 + c], lg1);
      lg2 = fmaf(xv, gw[128 + c], lg2);
      lg3 = fmaf(xv, gw[192 + c], lg3);
    }
    float m = fmaxf(fmaxf(lg0, lg1), fmaxf(lg2, lg3));
    float e0 = expf(lg0 - m), e1 = expf(lg1 - m);
    float e2 = expf(lg2 - m), e3 = expf(lg3 - m);
    float inv = 1.0f / (e0 + e1 + e2 + e3);
    if (!((unsigned)grow < HH && (unsigned)gcol < WW)) inv = 0.0f;  // zero-pad mu
    mus[0][y][cx] = e0 * inv;
    mus[1][y][cx] = e1 * inv;
    mus[2][y][cx] = e2 * inv;
    mus[3][y][cx] = e3 * inv;
  }
  __syncthreads();

  // ---- phase B: raw alpha per (px, r) with in-register kern; write rsum
  float a9[9];
  {
    int t = tid & 63, r = tid >> 6;          // r wave-uniform
    float th = theta[r];
    float ct = cosf(th), st = sinf(th);
    float su = log1pf(expf(rsu[r])) + 1e-4f;
    float sv = log1pf(expf(rss[r])) + 1e-4f;
    float isu = 1.0f / (su * su), isv = 1.0f / (sv * sv);
    int prow = t >> 5, pcol = t & 31;
    float mc = mus[r][prow + 1][pcol + 4];
    float sum = 0.f;
    #pragma unroll
    for (int s = 0; s < 9; ++s) {
      float dy = (float)(s / 3 - 1), dx = (float)(s % 3 - 1);
      float pu = ct * dx + st * dy;
      float ps = -st * dx + ct * dy;
      float kern = expf(-pu * pu * isu - ps * ps * isv);
      float av = mc * mus[r][prow + s / 3][pcol + 3 + s % 3] * kern;
      a9[s] = av;
      sum += av;
    }
    rsum[(r << 6) + t] = sum;
  }
  __syncthreads();

  // ---- fold: normalize alpha, store bf16 [px][s*4+r]
  {
    int t = tid & 63, r = tid >> 6;
    float tot = rsum[t] + rsum[64 + t] + rsum[128 + t] + rsum[192 + t];
    float inv = 1.0f / fmaxf(tot, 1e-8f);
    #pragma unroll
    for (int s = 0; s < 9; ++s)
      alp[t][(s << 2) + r] = f2bf(a9[s] * inv);
  }
  __syncthreads();

  // ---- rounds: 4 x (C: 16-px agg -> D: MFMA); defer even-round stores so
  //      each 128B output line is written by two adjacent 64B stores (no
  //      partial-line write-allocate churn — R5's 3x HBM regression).
  f32x4 dprev0, dprev1;
  #pragma unroll
  for (int rd = 0; rd < 4; ++rd) {
    // phase C
    {
      int t16 = tid & 15, cg = tid >> 4, c0 = cg << 2;
      int px = (rd << 4) + t16;
      int prow2 = px >> 5, pc = px & 31;
      f32x2 cacc[4][2];
      #pragma unroll
      for (int r = 0; r < 4; ++r) {
        cacc[r][0] = (f32x2){0.f, 0.f};
        cacc[r][1] = (f32x2){0.f, 0.f};
      }
      const unsigned short* arow = &alp[px][0];
      #pragma unroll
      for (int s = 0; s < 9; ++s) {
        uint2 ad = *(const uint2*)(arow + (s << 2));
        float af0 = __uint_as_float(ad.x << 16);
        float af1 = __uint_as_float(ad.x & 0xffff0000u);
        float af2 = __uint_as_float(ad.y << 16);
        float af3 = __uint_as_float(ad.y & 0xffff0000u);
        int xo = (prow2 + s / 3) * 40 + pc + 3 + s % 3;
        f32x2 xv0, xv1;
        xv0[0] = bf2f(xs[c0][xo]);     xv0[1] = bf2f(xs[c0 + 1][xo]);
        xv1[0] = bf2f(xs[c0 + 2][xo]); xv1[1] = bf2f(xs[c0 + 3][xo]);
        f32x2 A0 = {af0, af0}, A1 = {af1, af1}, A2 = {af2, af2}, A3 = {af3, af3};
        cacc[0][0] += A0 * xv0; cacc[0][1] += A0 * xv1;
        cacc[1][0] += A1 * xv0; cacc[1][1] += A1 * xv1;
        cacc[2][0] += A2 * xv0; cacc[2][1] += A2 * xv1;
        cacc[3][0] += A3 * xv0; cacc[3][1] += A3 * xv1;
      }
      #pragma unroll
      for (int r = 0; r < 4; ++r) {
        ushort4 wvv;
        wvv.x = f2bf(cacc[r][0][0]); wvv.y = f2bf(cacc[r][0][1]);
        wvv.z = f2bf(cacc[r][1][0]); wvv.w = f2bf(cacc[r][1][1]);
        *(ushort4*)&aggs[t16][(r << 6) + c0] = wvv;
      }
    }
    __syncthreads();

    // phase D: 16-px GEMM slice
    {
      f32x4 dacc0 = (f32x4){0.f, 0.f, 0.f, 0.f};
      f32x4 dacc1 = (f32x4){0.f, 0.f, 0.f, 0.f};
      #pragma unroll
      for (int ks = 0; ks < 8; ++ks) {
        short8 b0 = *(const short8*)&aggs[lr][(ks << 5) + (lq << 3)];
        dacc0 = __builtin_amdgcn_mfma_f32_16x16x32_bf16(a0r[ks], b0, dacc0, 0, 0, 0);
        dacc1 = __builtin_amdgcn_mfma_f32_16x16x32_bf16(a1r[ks], b0, dacc1, 0, 0, 0);
      }
      if ((rd & 1) == 0) {
        dprev0 = dacc0; dprev1 = dacc1;
      } else {
        int orow = h0 + (rd >> 1);
        #pragma unroll
        for (int q = 0; q < 4; ++q) {
          int o = o0 + (lq << 2) + q;
          size_t base0 = (((size_t)b * COUT + o) << 14) + (orow << 7) + w0;
          size_t base1 = (((size_t)b * COUT + o + 16) << 14) + (orow << 7) + w0;
          out[base0 + lr]      = dprev0[q] + pbv0[q];
          out[base0 + 16 + lr] = dacc0[q] + pbv0[q];
          out[base1 + lr]      = dprev1[q] + pbv1[q];
          out[base1 + 16 + lr] = dacc1[q] + pbv1[q];
        }
      }
    }
    if (rd < 3) __syncthreads();
  }
}

extern "C" void kernel_launch(void* const* d_in, const int* in_sizes, int n_in,
                              void* d_out, int out_size, void* d_ws, size_t ws_size,
                              hipStream_t stream) {
  const float* x     = (const float*)d_in[0];
  const float* gw    = (const float*)d_in[1];
  const float* gb    = (const float*)d_in[2];
  const float* theta = (const float*)d_in[3];
  const float* rsu   = (const float*)d_in[4];
  const float* rss   = (const float*)d_in[5];
  const float* pw    = (const float*)d_in[6];
  const float* pb    = (const float*)d_in[7];
  float* outp = (float*)d_out;

  unsigned short* pwb = (unsigned short*)d_ws;   // 32768 bf16 = 64KB

  k_pre<<<(COUT * RR * CC) / 256, 256, 0, stream>>>(pw, pwb);
  k_fused<<<BB * (HH / 2) * (WW / 32), 256, 0, stream>>>(x, gw, gb, theta, rsu, rss,
                                                         pwb, pb, outp);
}

// Round 7
// 68.738 us; speedup vs baseline: 1.4653x; 1.1178x over previous
//
#include <hip/hip_runtime.h>
#include <math.h>

#define CC 64
#define RR 4
#define HH 128
#define WW 128
#define BB 8
#define COUT 128
#define XCH 164   // xs channel stride in ushorts (328B -> 2-way max on C reads)
#define ALS 44    // alp row stride in ushorts (88B = 22dw, gcd(22,32)=2 -> free; 8B-aligned)

typedef __attribute__((ext_vector_type(8))) short short8;
typedef __attribute__((ext_vector_type(4))) float f32x4;
typedef __attribute__((ext_vector_type(2))) float f32x2;

__device__ __forceinline__ unsigned short f2bf(float f) {
  unsigned u = __float_as_uint(f);
  u += 0x7fffu + ((u >> 16) & 1u);
  return (unsigned short)(u >> 16);
}
__device__ __forceinline__ float bf2f(unsigned short h) {
  return __uint_as_float(((unsigned)h) << 16);
}

// --- K0: pw -> bf16
__global__ __launch_bounds__(256) void k_pre(const float* __restrict__ pw,
                                             unsigned short* __restrict__ pwb) {
  int i = blockIdx.x * 256 + threadIdx.x;
  pwb[i] = f2bf(pw[i]);
}

// --- K1: fully fused. tile: 2 rows x 32 cols; 2048 blocks; 3 blocks/CU (R4 structure)
__global__ __launch_bounds__(256, 3) void k_fused(const float* __restrict__ x,
                                                  const float* __restrict__ gw,
                                                  const float* __restrict__ gb,
                                                  const float* __restrict__ theta,
                                                  const float* __restrict__ rsu,
                                                  const float* __restrict__ rss,
                                                  const unsigned short* __restrict__ pwb,
                                                  const float* __restrict__ pb,
                                                  float* __restrict__ out) {
  __shared__ unsigned short xs[CC][XCH];     // bf16 x halo [c][row*40+col]
  __shared__ float mus[RR][4][40];           // mu halo (cols 3..36 valid)
  __shared__ unsigned short alp[64][ALS];    // RAW bf16 alpha [px][s*4+r]
  __shared__ float rsum[RR][64];             // per-r raw-alpha sums
  __shared__ __align__(16) unsigned short aggs[32][264];  // bf16 agg per 32-px round

  int tid = threadIdx.x;
  int raw = blockIdx.x;
  int bid = (raw & 7) * 256 + (raw >> 3);    // XCD swizzle (2048 % 8 == 0)
  int b = bid >> 8;
  int rem = bid & 255;
  int h0 = (rem >> 2) << 1;                  // 64 h-tiles of 2 rows
  int w0 = (rem & 3) << 5;                   // 4 w-tiles of 32 cols

  int lane = tid & 63;
  int wv = tid >> 6;
  int lr = lane & 15, lq = lane >> 4;
  int o0 = wv << 5;

  // ---- A-fragments + bias preload (as R4; compiler may remat from L2-hot pwb)
  short8 a0r[8], a1r[8];
  {
    const unsigned short* pA = pwb + ((o0 + lr) << 8) + (lq << 3);
    #pragma unroll
    for (int ks = 0; ks < 8; ++ks) {
      a0r[ks] = *(const short8*)(pA + (ks << 5));
      a1r[ks] = *(const short8*)(pA + 4096 + (ks << 5));
    }
  }
  float4 pbv0 = *(const float4*)&pb[o0 + (lq << 2)];
  float4 pbv1 = *(const float4*)&pb[o0 + 16 + (lq << 2)];

  // ---- phase A: stage x halo as float4 -> bf16x4 (R4 mapping)
  {
    int c4 = tid & 15;             // f4 slot (10 active)
    int pr0 = tid >> 4;            // 0..15
    if (c4 < 10) {
      int gcol = w0 - 4 + (c4 << 2);
      bool colok = (unsigned)gcol < WW;
      #pragma unroll
      for (int k = 0; k < 16; ++k) {
        int pair = (k << 4) + pr0;         // 0..255 = (c,row)
        int c = pair >> 2, row = pair & 3;
        int grow = h0 - 1 + row;
        float4 v = make_float4(0.f, 0.f, 0.f, 0.f);
        if (colok && (unsigned)grow < HH)
          v = *(const float4*)(x + (((size_t)b * CC + c) << 14) + (grow << 7) + gcol);
        ushort4 uv;
        uv.x = f2bf(v.x); uv.y = f2bf(v.y); uv.z = f2bf(v.z); uv.w = f2bf(v.w);
        *(ushort4*)&xs[c][row * 40 + (c4 << 2)] = uv;
      }
    }
  }
  __syncthreads();

  // ---- phase Mu: softmax gate for the 4x34 halo
  if (tid < 136) {
    int y = tid / 34, cxo = tid % 34;
    int cx = 3 + cxo;
    int grow = h0 - 1 + y, gcol = w0 - 1 + cxo;
    float lg0 = gb[0], lg1 = gb[1], lg2 = gb[2], lg3 = gb[3];
    #pragma unroll 16
    for (int c = 0; c < CC; ++c) {
      float xv = bf2f(xs[c][y * 40 + cx]);
      lg0 = fmaf(xv, gw[c], lg0);
      lg1 = fmaf(xv, gw[64 + c], lg1);
      lg2 = fmaf(xv, gw[128 + c], lg2);
      lg3 = fmaf(xv, gw[192 + c], lg3);
    }
    float m = fmaxf(fmaxf(lg0, lg1), fmaxf(lg2, lg3));
    float e0 = expf(lg0 - m), e1 = expf(lg1 - m);
    float e2 = expf(lg2 - m), e3 = expf(lg3 - m);
    float inv = 1.0f / (e0 + e1 + e2 + e3);
    if (!((unsigned)grow < HH && (unsigned)gcol < WW)) inv = 0.0f;  // zero-pad mu
    mus[0][y][cx] = e0 * inv;
    mus[1][y][cx] = e1 * inv;
    mus[2][y][cx] = e2 * inv;
    mus[3][y][cx] = e3 * inv;
  }
  __syncthreads();

  // ---- phase B: raw alpha (bf16) per (px, r), in-register kern; write rsum
  {
    int t = tid & 63, r = tid >> 6;          // r wave-uniform
    float th = theta[r];
    float ct = cosf(th), st = sinf(th);
    float su = log1pf(expf(rsu[r])) + 1e-4f;
    float sv = log1pf(expf(rss[r])) + 1e-4f;
    float isu = 1.0f / (su * su), isv = 1.0f / (sv * sv);
    int prow = t >> 5, pcol = t & 31;
    float mc = mus[r][prow + 1][pcol + 4];
    float sum = 0.f;
    #pragma unroll
    for (int s = 0; s < 9; ++s) {
      float dy = (float)(s / 3 - 1), dx = (float)(s % 3 - 1);
      float pu = ct * dx + st * dy;
      float ps = -st * dx + ct * dy;
      float kern = expf(-pu * pu * isu - ps * ps * isv);
      float av = mc * mus[r][prow + s / 3][pcol + 3 + s % 3] * kern;
      alp[t][(s << 2) + r] = f2bf(av);
      sum += av;
    }
    rsum[r][t] = sum;
  }
  __syncthreads();

  #pragma unroll
  for (int p = 0; p < 2; ++p) {
    // ---- phase C: agg (normalization folded into pack), pipelined LDS reads
    {
      int t = tid & 31, cg = tid >> 5, c0 = cg << 3;
      int px = (p << 5) + t;
      float inv = 1.0f / fmaxf(rsum[0][px] + rsum[1][px] + rsum[2][px] + rsum[3][px], 1e-8f);

      // all 9 alpha uint2 up front (independent -> one latency)
      uint2 ad[9];
      #pragma unroll
      for (int s = 0; s < 9; ++s) ad[s] = *(const uint2*)(&alp[px][s << 2]);

      f32x2 cacc[4][4];
      #pragma unroll
      for (int r = 0; r < 4; ++r)
        #pragma unroll
        for (int j = 0; j < 4; ++j) cacc[r][j] = (f32x2){0.f, 0.f};

      // double-buffered xs batches across s
      f32x2 xv[2][4];
      {
        int xo = p * 40 + t + 3;             // s = 0
        #pragma unroll
        for (int j = 0; j < 4; ++j) {
          xv[0][j][0] = bf2f(xs[c0 + 2 * j][xo]);
          xv[0][j][1] = bf2f(xs[c0 + 2 * j + 1][xo]);
        }
      }
      #pragma unroll
      for (int s = 0; s < 9; ++s) {
        if (s < 8) {
          int sn = s + 1;
          int xo = (p + sn / 3) * 40 + t + 3 + sn % 3;
          #pragma unroll
          for (int j = 0; j < 4; ++j) {
            xv[(s + 1) & 1][j][0] = bf2f(xs[c0 + 2 * j][xo]);
            xv[(s + 1) & 1][j][1] = bf2f(xs[c0 + 2 * j + 1][xo]);
          }
        }
        unsigned adx = ad[s].x, ady = ad[s].y;
        float af0 = __uint_as_float(adx << 16);
        float af1 = __uint_as_float(adx & 0xffff0000u);
        float af2 = __uint_as_float(ady << 16);
        float af3 = __uint_as_float(ady & 0xffff0000u);
        f32x2 A0 = {af0, af0}, A1 = {af1, af1}, A2 = {af2, af2}, A3 = {af3, af3};
        #pragma unroll
        for (int j = 0; j < 4; ++j) {
          f32x2 xvj = xv[s & 1][j];
          cacc[0][j] += A0 * xvj;
          cacc[1][j] += A1 * xvj;
          cacc[2][j] += A2 * xvj;
          cacc[3][j] += A3 * xvj;
        }
      }
      #pragma unroll
      for (int r = 0; r < 4; ++r) {
        short8 wvv;
        #pragma unroll
        for (int j = 0; j < 4; ++j) {
          wvv[2 * j]     = (short)f2bf(cacc[r][j][0] * inv);
          wvv[2 * j + 1] = (short)f2bf(cacc[r][j][1] * inv);
        }
        *(short8*)&aggs[t][(r << 6) + c0] = wvv;
      }
    }
    __syncthreads();

    // ---- phase D: out[128][32] = pwb @ aggs^T via mfma 16x16x32 bf16 (4 chains)
    f32x4 dacc[2][2];
    #pragma unroll
    for (int i = 0; i < 2; ++i)
      #pragma unroll
      for (int j = 0; j < 2; ++j) dacc[i][j] = (f32x4){0.f, 0.f, 0.f, 0.f};

    #pragma unroll
    for (int ks = 0; ks < 8; ++ks) {
      short8 b0 = *(const short8*)&aggs[lr][(ks << 5) + (lq << 3)];
      short8 b1 = *(const short8*)&aggs[16 + lr][(ks << 5) + (lq << 3)];
      dacc[0][0] = __builtin_amdgcn_mfma_f32_16x16x32_bf16(a0r[ks], b0, dacc[0][0], 0, 0, 0);
      dacc[0][1] = __builtin_amdgcn_mfma_f32_16x16x32_bf16(a0r[ks], b1, dacc[0][1], 0, 0, 0);
      dacc[1][0] = __builtin_amdgcn_mfma_f32_16x16x32_bf16(a1r[ks], b0, dacc[1][0], 0, 0, 0);
      dacc[1][1] = __builtin_amdgcn_mfma_f32_16x16x32_bf16(a1r[ks], b1, dacc[1][1], 0, 0, 0);
    }

    // epilogue: full 128B line per channel-row in one burst (R4 pattern)
    #pragma unroll
    for (int oi = 0; oi < 2; ++oi) {
      float4 pbv = oi ? pbv1 : pbv0;
      #pragma unroll
      for (int q = 0; q < 4; ++q) {
        int o = o0 + (oi << 4) + (lq << 2) + q;
        size_t base = (((size_t)b * COUT + o) << 14) + ((h0 + p) << 7) + w0;
        out[base + lr]      = dacc[oi][0][q] + pbv[q];
        out[base + 16 + lr] = dacc[oi][1][q] + pbv[q];
      }
    }
    if (p == 0) __syncthreads();   // protect aggs before next round's phase C
  }
}

extern "C" void kernel_launch(void* const* d_in, const int* in_sizes, int n_in,
                              void* d_out, int out_size, void* d_ws, size_t ws_size,
                              hipStream_t stream) {
  const float* x     = (const float*)d_in[0];
  const float* gw    = (const float*)d_in[1];
  const float* gb    = (const float*)d_in[2];
  const float* theta = (const float*)d_in[3];
  const float* rsu   = (const float*)d_in[4];
  const float* rss   = (const float*)d_in[5];
  const float* pw    = (const float*)d_in[6];
  const float* pb    = (const float*)d_in[7];
  float* outp = (float*)d_out;

  unsigned short* pwb = (unsigned short*)d_ws;   // 32768 bf16 = 64KB

  k_pre<<<(COUT * RR * CC) / 256, 256, 0, stream>>>(pw, pwb);
  k_fused<<<BB * (HH / 2) * (WW / 32), 256, 0, stream>>>(x, gw, gb, theta, rsu, rss,
                                                         pwb, pb, outp);
}

// Round 8
// 66.092 us; speedup vs baseline: 1.5239x; 1.0400x over previous
//
#include <hip/hip_runtime.h>
#include <math.h>

#define CC 64
#define RR 4
#define HH 128
#define WW 128
#define BB 8
#define COUT 128
#define XCH 164   // xs channel stride in ushorts (328B = 82 dw, gcd 2 -> 2-way free)
#define ALS 44    // alp row stride in ushorts (88B = 22 dw; uint2-aligned rows)

typedef __attribute__((ext_vector_type(8))) short short8;
typedef __attribute__((ext_vector_type(4))) float f32x4;
typedef __attribute__((ext_vector_type(2))) float f32x2;

__device__ __forceinline__ unsigned short f2bf(float f) {
  unsigned u = __float_as_uint(f);
  u += 0x7fffu + ((u >> 16) & 1u);
  return (unsigned short)(u >> 16);
}
__device__ __forceinline__ float bf2f(unsigned short h) {
  return __uint_as_float(((unsigned)h) << 16);
}

// --- K0: kern table (36 floats) + pw -> bf16
__global__ __launch_bounds__(256) void k_pre(const float* __restrict__ theta,
                                             const float* __restrict__ rsu,
                                             const float* __restrict__ rss,
                                             const float* __restrict__ pw,
                                             float* __restrict__ wkern,
                                             unsigned short* __restrict__ pwb) {
  int i = blockIdx.x * 256 + threadIdx.x;
  if (i < COUT * RR * CC) pwb[i] = f2bf(pw[i]);
  if (blockIdx.x == 0 && threadIdx.x < RR * 9) {
    int t = threadIdx.x;
    int r = t / 9, s = t % 9;
    float dy = (float)(s / 3 - 1), dx = (float)(s % 3 - 1);
    float ct = cosf(theta[r]), st = sinf(theta[r]);
    float su = log1pf(expf(rsu[r])) + 1e-4f;
    float sv = log1pf(expf(rss[r])) + 1e-4f;
    float pu = ct * dx + st * dy;
    float ps = -st * dx + ct * dy;
    wkern[t] = expf(-(pu * pu) / (su * su) - (ps * ps) / (sv * sv));
  }
}

// --- K1: fully fused. tile: 2 rows x 32 cols; 2048 blocks; 38.7KB LDS -> 4 blocks/CU
__global__ __launch_bounds__(256, 3) void k_fused(const float* __restrict__ x,
                                                  const float* __restrict__ gw,
                                                  const float* __restrict__ gb,
                                                  const float* __restrict__ wkern,
                                                  const unsigned short* __restrict__ pwb,
                                                  const float* __restrict__ pb,
                                                  float* __restrict__ out) {
  __shared__ unsigned short xs[CC][XCH];     // bf16 x halo [c][row*40+col]
  __shared__ float mus[RR][4][40];           // mu halo (cols 3..36 valid)
  __shared__ unsigned short alp[64][ALS];    // RAW bf16 alpha [px][s*4+r]
  __shared__ float rsum[RR][64];             // per-r raw-alpha sums
  __shared__ __align__(16) unsigned short aggs[16][264];  // bf16 agg per 16-px round

  int tid = threadIdx.x;
  int raw = blockIdx.x;
  int bid = (raw & 7) * 256 + (raw >> 3);    // XCD swizzle (2048 % 8 == 0)
  int b = bid >> 8;
  int rem = bid & 255;
  int h0 = (rem >> 2) << 1;                  // 64 h-tiles of 2 rows
  int w0 = (rem & 3) << 5;                   // 4 w-tiles of 32 cols

  int lane = tid & 63;
  int wv = tid >> 6;
  int lr = lane & 15, lq = lane >> 4;
  int o0 = wv << 5;

  // ---- A-fragments + bias preload
  short8 a0r[8], a1r[8];
  {
    const unsigned short* pA = pwb + ((o0 + lr) << 8) + (lq << 3);
    #pragma unroll
    for (int ks = 0; ks < 8; ++ks) {
      a0r[ks] = *(const short8*)(pA + (ks << 5));
      a1r[ks] = *(const short8*)(pA + 4096 + (ks << 5));
    }
  }
  float4 pbv0 = *(const float4*)&pb[o0 + (lq << 2)];
  float4 pbv1 = *(const float4*)&pb[o0 + 16 + (lq << 2)];

  // ---- phase A: stage x halo as float4 -> bf16x4 (R4 mapping)
  {
    int c4 = tid & 15;             // f4 slot (10 active)
    int pr0 = tid >> 4;            // 0..15
    if (c4 < 10) {
      int gcol = w0 - 4 + (c4 << 2);
      bool colok = (unsigned)gcol < WW;
      #pragma unroll
      for (int k = 0; k < 16; ++k) {
        int pair = (k << 4) + pr0;         // 0..255 = (c,row)
        int c = pair >> 2, row = pair & 3;
        int grow = h0 - 1 + row;
        float4 v = make_float4(0.f, 0.f, 0.f, 0.f);
        if (colok && (unsigned)grow < HH)
          v = *(const float4*)(x + (((size_t)b * CC + c) << 14) + (grow << 7) + gcol);
        ushort4 uv;
        uv.x = f2bf(v.x); uv.y = f2bf(v.y); uv.z = f2bf(v.z); uv.w = f2bf(v.w);
        *(ushort4*)&xs[c][row * 40 + (c4 << 2)] = uv;
      }
    }
  }
  __syncthreads();

  // ---- phase Mu: softmax gate for the 4x34 halo
  if (tid < 136) {
    int y = tid / 34, cxo = tid % 34;
    int cx = 3 + cxo;
    int grow = h0 - 1 + y, gcol = w0 - 1 + cxo;
    float lg0 = gb[0], lg1 = gb[1], lg2 = gb[2], lg3 = gb[3];
    #pragma unroll 8
    for (int c = 0; c < CC; ++c) {
      float xv = bf2f(xs[c][y * 40 + cx]);
      lg0 = fmaf(xv, gw[c], lg0);
      lg1 = fmaf(xv, gw[64 + c], lg1);
      lg2 = fmaf(xv, gw[128 + c], lg2);
      lg3 = fmaf(xv, gw[192 + c], lg3);
    }
    float m = fmaxf(fmaxf(lg0, lg1), fmaxf(lg2, lg3));
    float e0 = expf(lg0 - m), e1 = expf(lg1 - m);
    float e2 = expf(lg2 - m), e3 = expf(lg3 - m);
    float inv = 1.0f / (e0 + e1 + e2 + e3);
    if (!((unsigned)grow < HH && (unsigned)gcol < WW)) inv = 0.0f;  // zero-pad mu
    mus[0][y][cx] = e0 * inv;
    mus[1][y][cx] = e1 * inv;
    mus[2][y][cx] = e2 * inv;
    mus[3][y][cx] = e3 * inv;
  }
  __syncthreads();

  // ---- phase B: raw alpha (bf16) per (px, r) from wkern table; write rsum
  {
    int t = tid & 63, r = tid >> 6;          // r wave-uniform -> wkern scalar loads
    int prow = t >> 5, pcol = t & 31;
    float mc = mus[r][prow + 1][pcol + 4];
    float sum = 0.f;
    #pragma unroll
    for (int s = 0; s < 9; ++s) {
      float av = mc * mus[r][prow + s / 3][pcol + 3 + s % 3] * wkern[r * 9 + s];
      alp[t][(s << 2) + r] = f2bf(av);
      sum += av;
    }
    rsum[r][t] = sum;
  }
  __syncthreads();

  // ---- rounds: 4 x (C: 16-px agg -> D: MFMA); even-round stores deferred so
  //      each 128B output line is written as two adjacent 64B bursts.
  f32x4 dprev0 = (f32x4){0.f, 0.f, 0.f, 0.f};
  f32x4 dprev1 = (f32x4){0.f, 0.f, 0.f, 0.f};
  #pragma unroll
  for (int rd = 0; rd < 4; ++rd) {
    // phase C: 16 px x 16 c-groups of 4c; normalization folded into pack
    {
      int t16 = tid & 15, cg = tid >> 4, c0 = cg << 2;
      int px = (rd << 4) + t16;
      int prow2 = px >> 5, pc = px & 31;
      float inv = 1.0f / fmaxf(rsum[0][px] + rsum[1][px] + rsum[2][px] + rsum[3][px], 1e-8f);

      uint2 ad[9];
      #pragma unroll
      for (int s = 0; s < 9; ++s) ad[s] = *(const uint2*)(&alp[px][s << 2]);

      f32x2 cacc[4][2];
      #pragma unroll
      for (int r = 0; r < 4; ++r) {
        cacc[r][0] = (f32x2){0.f, 0.f};
        cacc[r][1] = (f32x2){0.f, 0.f};
      }

      f32x2 xv[2][2];
      {
        int xo = prow2 * 40 + pc + 3;        // s = 0
        xv[0][0][0] = bf2f(xs[c0][xo]);     xv[0][0][1] = bf2f(xs[c0 + 1][xo]);
        xv[0][1][0] = bf2f(xs[c0 + 2][xo]); xv[0][1][1] = bf2f(xs[c0 + 3][xo]);
      }
      #pragma unroll
      for (int s = 0; s < 9; ++s) {
        if (s < 8) {
          int sn = s + 1;
          int xo = (prow2 + sn / 3) * 40 + pc + 3 + sn % 3;
          xv[(s + 1) & 1][0][0] = bf2f(xs[c0][xo]);
          xv[(s + 1) & 1][0][1] = bf2f(xs[c0 + 1][xo]);
          xv[(s + 1) & 1][1][0] = bf2f(xs[c0 + 2][xo]);
          xv[(s + 1) & 1][1][1] = bf2f(xs[c0 + 3][xo]);
        }
        unsigned adx = ad[s].x, ady = ad[s].y;
        float af0 = __uint_as_float(adx << 16);
        float af1 = __uint_as_float(adx & 0xffff0000u);
        float af2 = __uint_as_float(ady << 16);
        float af3 = __uint_as_float(ady & 0xffff0000u);
        f32x2 A0 = {af0, af0}, A1 = {af1, af1}, A2 = {af2, af2}, A3 = {af3, af3};
        f32x2 x0 = xv[s & 1][0], x1 = xv[s & 1][1];
        cacc[0][0] += A0 * x0; cacc[0][1] += A0 * x1;
        cacc[1][0] += A1 * x0; cacc[1][1] += A1 * x1;
        cacc[2][0] += A2 * x0; cacc[2][1] += A2 * x1;
        cacc[3][0] += A3 * x0; cacc[3][1] += A3 * x1;
      }
      #pragma unroll
      for (int r = 0; r < 4; ++r) {
        ushort4 wvv;
        wvv.x = f2bf(cacc[r][0][0] * inv); wvv.y = f2bf(cacc[r][0][1] * inv);
        wvv.z = f2bf(cacc[r][1][0] * inv); wvv.w = f2bf(cacc[r][1][1] * inv);
        *(ushort4*)&aggs[t16][(r << 6) + c0] = wvv;
      }
    }
    __syncthreads();

    // phase D: 16-px GEMM slice
    {
      f32x4 dacc0 = (f32x4){0.f, 0.f, 0.f, 0.f};
      f32x4 dacc1 = (f32x4){0.f, 0.f, 0.f, 0.f};
      #pragma unroll
      for (int ks = 0; ks < 8; ++ks) {
        short8 b0 = *(const short8*)&aggs[lr][(ks << 5) + (lq << 3)];
        dacc0 = __builtin_amdgcn_mfma_f32_16x16x32_bf16(a0r[ks], b0, dacc0, 0, 0, 0);
        dacc1 = __builtin_amdgcn_mfma_f32_16x16x32_bf16(a1r[ks], b0, dacc1, 0, 0, 0);
      }
      if ((rd & 1) == 0) {
        dprev0 = dacc0; dprev1 = dacc1;
      } else {
        int orow = h0 + (rd >> 1);
        #pragma unroll
        for (int q = 0; q < 4; ++q) {
          int o = o0 + (lq << 2) + q;
          size_t base0 = (((size_t)b * COUT + o) << 14) + (orow << 7) + w0;
          size_t base1 = (((size_t)b * COUT + o + 16) << 14) + (orow << 7) + w0;
          out[base0 + lr]      = dprev0[q] + pbv0[q];
          out[base0 + 16 + lr] = dacc0[q] + pbv0[q];
          out[base1 + lr]      = dprev1[q] + pbv1[q];
          out[base1 + 16 + lr] = dacc1[q] + pbv1[q];
        }
      }
    }
    if (rd < 3) __syncthreads();
  }
}

extern "C" void kernel_launch(void* const* d_in, const int* in_sizes, int n_in,
                              void* d_out, int out_size, void* d_ws, size_t ws_size,
                              hipStream_t stream) {
  const float* x     = (const float*)d_in[0];
  const float* gw    = (const float*)d_in[1];
  const float* gb    = (const float*)d_in[2];
  const float* theta = (const float*)d_in[3];
  const float* rsu   = (const float*)d_in[4];
  const float* rss   = (const float*)d_in[5];
  const float* pw    = (const float*)d_in[6];
  const float* pb    = (const float*)d_in[7];
  float* outp = (float*)d_out;

  float* wkern = (float*)d_ws;                         // 64 floats
  unsigned short* pwb = (unsigned short*)(wkern + 64); // 32768 bf16

  k_pre<<<128, 256, 0, stream>>>(theta, rsu, rss, pw, wkern, pwb);
  k_fused<<<BB * (HH / 2) * (WW / 32), 256, 0, stream>>>(x, gw, gb, wkern, pwb, pb, outp);
}

// Round 9
// 60.242 us; speedup vs baseline: 1.6719x; 1.0971x over previous
//
#include <hip/hip_runtime.h>
#include <math.h>

#define CC 64
#define RR 4
#define HH 128
#define WW 128
#define BB 8
#define COUT 128
#define XCH 164   // xs channel stride in ushorts (328B = 82 dw, gcd 2 -> 2-way free)
#define ALS 44    // alp row stride in ushorts (88B = 22 dw; uint2-aligned rows)

typedef __attribute__((ext_vector_type(8))) short short8;
typedef __attribute__((ext_vector_type(4))) float f32x4;
typedef __attribute__((ext_vector_type(2))) float f32x2;

__device__ __forceinline__ unsigned short f2bf(float f) {
  unsigned u = __float_as_uint(f);
  u += 0x7fffu + ((u >> 16) & 1u);
  return (unsigned short)(u >> 16);
}
__device__ __forceinline__ float bf2f(unsigned short h) {
  return __uint_as_float(((unsigned)h) << 16);
}

// --- K0: kern table (36 floats) + pw -> bf16 + zero-padded gw -> bf16 [16][64]
__global__ __launch_bounds__(256) void k_pre(const float* __restrict__ theta,
                                             const float* __restrict__ rsu,
                                             const float* __restrict__ rss,
                                             const float* __restrict__ pw,
                                             const float* __restrict__ gw,
                                             float* __restrict__ wkern,
                                             unsigned short* __restrict__ pwb,
                                             unsigned short* __restrict__ gwb) {
  int i = blockIdx.x * 256 + threadIdx.x;
  if (i < COUT * RR * CC) pwb[i] = f2bf(pw[i]);
  if (blockIdx.x == 0 && threadIdx.x < RR * 9) {
    int t = threadIdx.x;
    int r = t / 9, s = t % 9;
    float dy = (float)(s / 3 - 1), dx = (float)(s % 3 - 1);
    float ct = cosf(theta[r]), st = sinf(theta[r]);
    float su = log1pf(expf(rsu[r])) + 1e-4f;
    float sv = log1pf(expf(rss[r])) + 1e-4f;
    float pu = ct * dx + st * dy;
    float ps = -st * dx + ct * dy;
    wkern[t] = expf(-(pu * pu) / (su * su) - (ps * ps) / (sv * sv));
  }
  if (blockIdx.x == 1) {
    #pragma unroll
    for (int k = 0; k < 4; ++k) {
      int j = k * 256 + threadIdx.x;     // 0..1023 over [16][64]
      gwb[j] = (j < RR * CC) ? f2bf(gw[j]) : (unsigned short)0;
    }
  }
}

// --- K1: fully fused. tile: 2 rows x 32 cols; 2048 blocks
__global__ __launch_bounds__(256, 3) void k_fused(const float* __restrict__ x,
                                                  const float* __restrict__ gwb_unused,
                                                  const float* __restrict__ gb,
                                                  const float* __restrict__ wkern,
                                                  const unsigned short* __restrict__ pwb,
                                                  const unsigned short* __restrict__ gwb,
                                                  const float* __restrict__ pb,
                                                  float* __restrict__ out) {
  __shared__ unsigned short xs[CC][XCH];     // bf16 x halo [c][row*40+col]
  __shared__ float mus[RR][4][40];           // mu halo (cols 3..36 valid)
  __shared__ unsigned short alp[64][ALS];    // RAW bf16 alpha [px][s*4+r]
  __shared__ float rsum[RR][64];             // per-r raw-alpha sums
  __shared__ __align__(16) unsigned short aggs[16][264];  // bf16 agg per 16-px round

  int tid = threadIdx.x;
  int raw = blockIdx.x;
  int bid = (raw & 7) * 256 + (raw >> 3);    // XCD swizzle (2048 % 8 == 0)
  int b = bid >> 8;
  int rem = bid & 255;
  int h0 = (rem >> 2) << 1;                  // 64 h-tiles of 2 rows
  int w0 = (rem & 3) << 5;                   // 4 w-tiles of 32 cols

  int lane = tid & 63;
  int wv = tid >> 6;
  int lr = lane & 15, lq = lane >> 4;
  int o0 = wv << 5;

  // ---- A-fragments (GEMM) + mu A-fragments + bias preload
  short8 a0r[8], a1r[8];
  {
    const unsigned short* pA = pwb + ((o0 + lr) << 8) + (lq << 3);
    #pragma unroll
    for (int ks = 0; ks < 8; ++ks) {
      a0r[ks] = *(const short8*)(pA + (ks << 5));
      a1r[ks] = *(const short8*)(pA + 4096 + (ks << 5));
    }
  }
  short8 am0 = *(const short8*)(gwb + (lr << 6) + (lq << 3));
  short8 am1 = *(const short8*)(gwb + (lr << 6) + 32 + (lq << 3));
  float4 pbv0 = *(const float4*)&pb[o0 + (lq << 2)];
  float4 pbv1 = *(const float4*)&pb[o0 + 16 + (lq << 2)];
  float gb0 = gb[0], gb1 = gb[1], gb2 = gb[2], gb3 = gb[3];

  // ---- phase A: stage x halo; exact cover of 2560 float4s by 256 lanes x 10 iters
  #pragma unroll
  for (int k = 0; k < 10; ++k) {
    unsigned idx = (unsigned)(k * 256 + tid);   // 0..2559
    unsigned c4 = idx % 10u;                    // f4 slot in row (0..9)
    unsigned pair = idx / 10u;                  // (c,row) 0..255
    int c = pair >> 2, row = pair & 3;
    int gcol = w0 - 4 + (c4 << 2);
    int grow = h0 - 1 + row;
    float4 v = make_float4(0.f, 0.f, 0.f, 0.f);
    if ((unsigned)gcol < WW && (unsigned)grow < HH)
      v = *(const float4*)(x + (((size_t)b * CC + c) << 14) + (grow << 7) + gcol);
    ushort4 uv;
    uv.x = f2bf(v.x); uv.y = f2bf(v.y); uv.z = f2bf(v.z); uv.w = f2bf(v.w);
    *(ushort4*)&xs[c][row * 40 + (c4 << 2)] = uv;
  }
  __syncthreads();

  // ---- phase Mu (MFMA): logits[16 gates pad][136 pos] = gwb @ xs-cols
  // 9 tiles of 16 positions over 4 waves; softmax fully in-lane (lq==0 lanes)
  for (int j = wv; j < 9; j += 4) {
    int p = (j << 4) + lr;
    int pcl = p > 135 ? 135 : p;
    unsigned y = (unsigned)pcl / 34u;
    int cxo = pcl - (int)(y * 34u);
    int pos = (int)y * 40 + 3 + cxo;
    short8 b0, b1;
    #pragma unroll
    for (int i = 0; i < 8; ++i) {
      b0[i] = (short)xs[(lq << 3) + i][pos];
      b1[i] = (short)xs[32 + (lq << 3) + i][pos];
    }
    f32x4 mac = (f32x4){0.f, 0.f, 0.f, 0.f};
    mac = __builtin_amdgcn_mfma_f32_16x16x32_bf16(am0, b0, mac, 0, 0, 0);
    mac = __builtin_amdgcn_mfma_f32_16x16x32_bf16(am1, b1, mac, 0, 0, 0);
    if (lq == 0 && p < 136) {
      int grow = h0 - 1 + (int)y, gcol = w0 - 1 + cxo;
      float lg0 = mac[0] + gb0, lg1 = mac[1] + gb1;
      float lg2 = mac[2] + gb2, lg3 = mac[3] + gb3;
      float m = fmaxf(fmaxf(lg0, lg1), fmaxf(lg2, lg3));
      float e0 = expf(lg0 - m), e1 = expf(lg1 - m);
      float e2 = expf(lg2 - m), e3 = expf(lg3 - m);
      float inv = 1.0f / (e0 + e1 + e2 + e3);
      if (!((unsigned)grow < HH && (unsigned)gcol < WW)) inv = 0.0f;  // zero-pad mu
      mus[0][y][3 + cxo] = e0 * inv;
      mus[1][y][3 + cxo] = e1 * inv;
      mus[2][y][3 + cxo] = e2 * inv;
      mus[3][y][3 + cxo] = e3 * inv;
    }
  }
  __syncthreads();

  // ---- phase B: raw alpha (bf16) per (px, r) from wkern table; write rsum
  {
    int t = tid & 63, r = tid >> 6;          // r wave-uniform -> wkern scalar loads
    int prow = t >> 5, pcol = t & 31;
    float mc = mus[r][prow + 1][pcol + 4];
    float sum = 0.f;
    #pragma unroll
    for (int s = 0; s < 9; ++s) {
      float av = mc * mus[r][prow + s / 3][pcol + 3 + s % 3] * wkern[r * 9 + s];
      alp[t][(s << 2) + r] = f2bf(av);
      sum += av;
    }
    rsum[r][t] = sum;
  }
  __syncthreads();

  // ---- rounds: 4 x (C: 16-px agg -> D: MFMA); even-round stores deferred so
  //      each 128B output line is written as two adjacent 64B bursts.
  f32x4 dprev0 = (f32x4){0.f, 0.f, 0.f, 0.f};
  f32x4 dprev1 = (f32x4){0.f, 0.f, 0.f, 0.f};
  #pragma unroll
  for (int rd = 0; rd < 4; ++rd) {
    // phase C: 16 px x 16 c-groups of 4c; normalization folded into pack
    {
      int t16 = tid & 15, cg = tid >> 4, c0 = cg << 2;
      int px = (rd << 4) + t16;
      int prow2 = px >> 5, pc = px & 31;
      float inv = 1.0f / fmaxf(rsum[0][px] + rsum[1][px] + rsum[2][px] + rsum[3][px], 1e-8f);

      uint2 ad[9];
      #pragma unroll
      for (int s = 0; s < 9; ++s) ad[s] = *(const uint2*)(&alp[px][s << 2]);

      f32x2 cacc[4][2];
      #pragma unroll
      for (int r = 0; r < 4; ++r) {
        cacc[r][0] = (f32x2){0.f, 0.f};
        cacc[r][1] = (f32x2){0.f, 0.f};
      }

      f32x2 xv[2][2];
      {
        int xo = prow2 * 40 + pc + 3;        // s = 0
        xv[0][0][0] = bf2f(xs[c0][xo]);     xv[0][0][1] = bf2f(xs[c0 + 1][xo]);
        xv[0][1][0] = bf2f(xs[c0 + 2][xo]); xv[0][1][1] = bf2f(xs[c0 + 3][xo]);
      }
      #pragma unroll
      for (int s = 0; s < 9; ++s) {
        if (s < 8) {
          int sn = s + 1;
          int xo = (prow2 + sn / 3) * 40 + pc + 3 + sn % 3;
          xv[(s + 1) & 1][0][0] = bf2f(xs[c0][xo]);
          xv[(s + 1) & 1][0][1] = bf2f(xs[c0 + 1][xo]);
          xv[(s + 1) & 1][1][0] = bf2f(xs[c0 + 2][xo]);
          xv[(s + 1) & 1][1][1] = bf2f(xs[c0 + 3][xo]);
        }
        unsigned adx = ad[s].x, ady = ad[s].y;
        float af0 = __uint_as_float(adx << 16);
        float af1 = __uint_as_float(adx & 0xffff0000u);
        float af2 = __uint_as_float(ady << 16);
        float af3 = __uint_as_float(ady & 0xffff0000u);
        f32x2 A0 = {af0, af0}, A1 = {af1, af1}, A2 = {af2, af2}, A3 = {af3, af3};
        f32x2 x0 = xv[s & 1][0], x1 = xv[s & 1][1];
        cacc[0][0] += A0 * x0; cacc[0][1] += A0 * x1;
        cacc[1][0] += A1 * x0; cacc[1][1] += A1 * x1;
        cacc[2][0] += A2 * x0; cacc[2][1] += A2 * x1;
        cacc[3][0] += A3 * x0; cacc[3][1] += A3 * x1;
      }
      #pragma unroll
      for (int r = 0; r < 4; ++r) {
        ushort4 wvv;
        wvv.x = f2bf(cacc[r][0][0] * inv); wvv.y = f2bf(cacc[r][0][1] * inv);
        wvv.z = f2bf(cacc[r][1][0] * inv); wvv.w = f2bf(cacc[r][1][1] * inv);
        *(ushort4*)&aggs[t16][(r << 6) + c0] = wvv;
      }
    }
    __syncthreads();

    // phase D: 16-px GEMM slice
    {
      f32x4 dacc0 = (f32x4){0.f, 0.f, 0.f, 0.f};
      f32x4 dacc1 = (f32x4){0.f, 0.f, 0.f, 0.f};
      #pragma unroll
      for (int ks = 0; ks < 8; ++ks) {
        short8 b0 = *(const short8*)&aggs[lr][(ks << 5) + (lq << 3)];
        dacc0 = __builtin_amdgcn_mfma_f32_16x16x32_bf16(a0r[ks], b0, dacc0, 0, 0, 0);
        dacc1 = __builtin_amdgcn_mfma_f32_16x16x32_bf16(a1r[ks], b0, dacc1, 0, 0, 0);
      }
      if ((rd & 1) == 0) {
        dprev0 = dacc0; dprev1 = dacc1;
      } else {
        int orow = h0 + (rd >> 1);
        #pragma unroll
        for (int q = 0; q < 4; ++q) {
          int o = o0 + (lq << 2) + q;
          size_t base0 = (((size_t)b * COUT + o) << 14) + (orow << 7) + w0;
          size_t base1 = (((size_t)b * COUT + o + 16) << 14) + (orow << 7) + w0;
          out[base0 + lr]      = dprev0[q] + pbv0[q];
          out[base0 + 16 + lr] = dacc0[q] + pbv0[q];
          out[base1 + lr]      = dprev1[q] + pbv1[q];
          out[base1 + 16 + lr] = dacc1[q] + pbv1[q];
        }
      }
    }
    if (rd < 3) __syncthreads();
  }
}

extern "C" void kernel_launch(void* const* d_in, const int* in_sizes, int n_in,
                              void* d_out, int out_size, void* d_ws, size_t ws_size,
                              hipStream_t stream) {
  const float* x     = (const float*)d_in[0];
  const float* gw    = (const float*)d_in[1];
  const float* gb    = (const float*)d_in[2];
  const float* theta = (const float*)d_in[3];
  const float* rsu   = (const float*)d_in[4];
  const float* rss   = (const float*)d_in[5];
  const float* pw    = (const float*)d_in[6];
  const float* pb    = (const float*)d_in[7];
  float* outp = (float*)d_out;

  float* wkern = (float*)d_ws;                           // 64 floats
  unsigned short* pwb = (unsigned short*)(wkern + 64);   // 32768 bf16
  unsigned short* gwb = pwb + COUT * RR * CC;            // 1024 bf16 [16][64]

  k_pre<<<128, 256, 0, stream>>>(theta, rsu, rss, pw, gw, wkern, pwb, gwb);
  k_fused<<<BB * (HH / 2) * (WW / 32), 256, 0, stream>>>(x, nullptr, gb, wkern,
                                                         pwb, gwb, pb, outp);
}

// Round 10
// 59.260 us; speedup vs baseline: 1.6996x; 1.0166x over previous
//
#include <hip/hip_runtime.h>
#include <math.h>

#define CC 64
#define RR 4
#define HH 128
#define WW 128
#define BB 8
#define COUT 128
#define XST 72    // xsT channel-dim stride in ushorts (144B rows, 16B-aligned)
#define ALS 44    // alp row stride in ushorts (88B, 8B-aligned)

typedef __attribute__((ext_vector_type(8))) short short8;
typedef __attribute__((ext_vector_type(4))) float f32x4;
typedef __attribute__((ext_vector_type(2))) float f32x2;

__device__ __forceinline__ unsigned short f2bf(float f) {
  unsigned u = __float_as_uint(f);
  u += 0x7fffu + ((u >> 16) & 1u);
  return (unsigned short)(u >> 16);
}
__device__ __forceinline__ float bf2f(unsigned short h) {
  return __uint_as_float(((unsigned)h) << 16);
}
__device__ __forceinline__ float blo(unsigned u) { return __uint_as_float(u << 16); }
__device__ __forceinline__ float bhi(unsigned u) { return __uint_as_float(u & 0xffff0000u); }

// --- K0: kern table + pw -> bf16 + zero-padded gw -> bf16 [16][64]
__global__ __launch_bounds__(256) void k_pre(const float* __restrict__ theta,
                                             const float* __restrict__ rsu,
                                             const float* __restrict__ rss,
                                             const float* __restrict__ pw,
                                             const float* __restrict__ gw,
                                             float* __restrict__ wkern,
                                             unsigned short* __restrict__ pwb,
                                             unsigned short* __restrict__ gwb) {
  int i = blockIdx.x * 256 + threadIdx.x;
  if (i < COUT * RR * CC) pwb[i] = f2bf(pw[i]);
  if (blockIdx.x == 0 && threadIdx.x < RR * 9) {
    int t = threadIdx.x;
    int r = t / 9, s = t % 9;
    float dy = (float)(s / 3 - 1), dx = (float)(s % 3 - 1);
    float ct = cosf(theta[r]), st = sinf(theta[r]);
    float su = log1pf(expf(rsu[r])) + 1e-4f;
    float sv = log1pf(expf(rss[r])) + 1e-4f;
    float pu = ct * dx + st * dy;
    float ps = -st * dx + ct * dy;
    wkern[t] = expf(-(pu * pu) / (su * su) - (ps * ps) / (sv * sv));
  }
  if (blockIdx.x == 1) {
    #pragma unroll
    for (int k = 0; k < 4; ++k) {
      int j = k * 256 + threadIdx.x;     // 0..1023 over [16][64]
      gwb[j] = (j < RR * CC) ? f2bf(gw[j]) : (unsigned short)0;
    }
  }
}

// --- K1: fully fused, TRANSPOSED x tile in LDS. 2 rows x 32 cols; 2048 blocks
__global__ __launch_bounds__(256, 3) void k_fused(const float* __restrict__ x,
                                                  const float* __restrict__ gb,
                                                  const float* __restrict__ wkern,
                                                  const unsigned short* __restrict__ pwb,
                                                  const unsigned short* __restrict__ gwb,
                                                  const float* __restrict__ pb,
                                                  float* __restrict__ out) {
  __shared__ unsigned short xsT[160][XST];   // bf16 x halo [spatial=row*40+col][channel]
  __shared__ float mus[RR][4][40];           // mu halo (cols 3..36 valid)
  __shared__ unsigned short alp[64][ALS];    // raw bf16 alpha [px][s*4+r]
  __shared__ float rsum[RR][64];             // per-r raw-alpha sums
  __shared__ __align__(16) unsigned short aggs[32][264];  // bf16 agg per 32-px round

  int tid = threadIdx.x;
  int raw = blockIdx.x;
  int bid = (raw & 7) * 256 + (raw >> 3);    // XCD swizzle (2048 % 8 == 0)
  int b = bid >> 8;
  int rem = bid & 255;
  int h0 = (rem >> 2) << 1;                  // 64 h-tiles of 2 rows
  int w0 = (rem & 3) << 5;                   // 4 w-tiles of 32 cols

  int lane = tid & 63;
  int wv = tid >> 6;
  int lr = lane & 15, lq = lane >> 4;
  int o0 = wv << 5;

  // ---- A-fragments (GEMM) + mu A-fragments + bias preload
  short8 a0r[8], a1r[8];
  {
    const unsigned short* pA = pwb + ((o0 + lr) << 8) + (lq << 3);
    #pragma unroll
    for (int ks = 0; ks < 8; ++ks) {
      a0r[ks] = *(const short8*)(pA + (ks << 5));
      a1r[ks] = *(const short8*)(pA + 4096 + (ks << 5));
    }
  }
  short8 am0 = *(const short8*)(gwb + (lr << 6) + (lq << 3));
  short8 am1 = *(const short8*)(gwb + (lr << 6) + 32 + (lq << 3));
  float4 pbv0 = *(const float4*)&pb[o0 + (lq << 2)];
  float4 pbv1 = *(const float4*)&pb[o0 + 16 + (lq << 2)];
  float gb0 = gb[0], gb1 = gb[1], gb2 = gb[2], gb3 = gb[3];

  // ---- phase A: stage x halo transposed; exact cover of 2560 float4s
  #pragma unroll
  for (int k = 0; k < 10; ++k) {
    unsigned idx = (unsigned)(k * 256 + tid);   // 0..2559
    unsigned c4 = idx % 10u;                    // f4 slot in row (0..9)
    unsigned pair = idx / 10u;                  // (c,row) 0..255
    int c = pair >> 2, row = pair & 3;
    int gcol = w0 - 4 + (c4 << 2);
    int grow = h0 - 1 + row;
    float4 v = make_float4(0.f, 0.f, 0.f, 0.f);
    if ((unsigned)gcol < WW && (unsigned)grow < HH)
      v = *(const float4*)(x + (((size_t)b * CC + c) << 14) + (grow << 7) + gcol);
    int sp = row * 40 + (c4 << 2);
    xsT[sp][c]     = f2bf(v.x);
    xsT[sp + 1][c] = f2bf(v.y);
    xsT[sp + 2][c] = f2bf(v.z);
    xsT[sp + 3][c] = f2bf(v.w);
  }
  __syncthreads();

  // ---- phase Mu (MFMA): logits = gwb @ xsT-cols; b-frags are b128 now
  for (int j = wv; j < 9; j += 4) {
    int p = (j << 4) + lr;
    int pcl = p > 135 ? 135 : p;
    unsigned y = (unsigned)pcl / 34u;
    int cxo = pcl - (int)(y * 34u);
    int pos = (int)y * 40 + 3 + cxo;
    short8 b0 = *(const short8*)&xsT[pos][lq << 3];
    short8 b1 = *(const short8*)&xsT[pos][32 + (lq << 3)];
    f32x4 mac = (f32x4){0.f, 0.f, 0.f, 0.f};
    mac = __builtin_amdgcn_mfma_f32_16x16x32_bf16(am0, b0, mac, 0, 0, 0);
    mac = __builtin_amdgcn_mfma_f32_16x16x32_bf16(am1, b1, mac, 0, 0, 0);
    if (lq == 0 && p < 136) {
      int grow = h0 - 1 + (int)y, gcol = w0 - 1 + cxo;
      float lg0 = mac[0] + gb0, lg1 = mac[1] + gb1;
      float lg2 = mac[2] + gb2, lg3 = mac[3] + gb3;
      float m = fmaxf(fmaxf(lg0, lg1), fmaxf(lg2, lg3));
      float e0 = expf(lg0 - m), e1 = expf(lg1 - m);
      float e2 = expf(lg2 - m), e3 = expf(lg3 - m);
      float inv = 1.0f / (e0 + e1 + e2 + e3);
      if (!((unsigned)grow < HH && (unsigned)gcol < WW)) inv = 0.0f;  // zero-pad mu
      mus[0][y][3 + cxo] = e0 * inv;
      mus[1][y][3 + cxo] = e1 * inv;
      mus[2][y][3 + cxo] = e2 * inv;
      mus[3][y][3 + cxo] = e3 * inv;
    }
  }
  __syncthreads();

  // ---- phase B: raw alpha (bf16) per (px, r) from wkern table; write rsum
  {
    int t = tid & 63, r = tid >> 6;          // r wave-uniform -> wkern scalar loads
    int prow = t >> 5, pcol = t & 31;
    float mc = mus[r][prow + 1][pcol + 4];
    float sum = 0.f;
    #pragma unroll
    for (int s = 0; s < 9; ++s) {
      float av = mc * mus[r][prow + s / 3][pcol + 3 + s % 3] * wkern[r * 9 + s];
      alp[t][(s << 2) + r] = f2bf(av);
      sum += av;
    }
    rsum[r][t] = sum;
  }
  __syncthreads();

  // ---- rounds: 2 x (C: 32-px agg -> D: MFMA + full-line stores)
  #pragma unroll
  for (int p = 0; p < 2; ++p) {
    // phase C: 32 px x 8 c-groups of 8 channels; one b128 per (s)
    {
      int t = tid & 31, cg = tid >> 5, c0 = cg << 3;
      int px = (p << 5) + t;
      float inv = 1.0f / fmaxf(rsum[0][px] + rsum[1][px] + rsum[2][px] + rsum[3][px], 1e-8f);

      uint2 ad[9];
      #pragma unroll
      for (int s = 0; s < 9; ++s) ad[s] = *(const uint2*)(&alp[px][s << 2]);

      f32x2 cacc[4][4];
      #pragma unroll
      for (int r = 0; r < 4; ++r)
        #pragma unroll
        for (int j = 0; j < 4; ++j) cacc[r][j] = (f32x2){0.f, 0.f};

      #pragma unroll
      for (int s = 0; s < 9; ++s) {
        uint4 ux = *(const uint4*)&xsT[(p + s / 3) * 40 + t + 3 + s % 3][c0];
        f32x2 xv0 = {blo(ux.x), bhi(ux.x)};
        f32x2 xv1 = {blo(ux.y), bhi(ux.y)};
        f32x2 xv2 = {blo(ux.z), bhi(ux.z)};
        f32x2 xv3 = {blo(ux.w), bhi(ux.w)};
        unsigned adx = ad[s].x, ady = ad[s].y;
        float af0 = blo(adx), af1 = bhi(adx), af2 = blo(ady), af3 = bhi(ady);
        f32x2 A0 = {af0, af0}, A1 = {af1, af1}, A2 = {af2, af2}, A3 = {af3, af3};
        cacc[0][0] += A0 * xv0; cacc[0][1] += A0 * xv1; cacc[0][2] += A0 * xv2; cacc[0][3] += A0 * xv3;
        cacc[1][0] += A1 * xv0; cacc[1][1] += A1 * xv1; cacc[1][2] += A1 * xv2; cacc[1][3] += A1 * xv3;
        cacc[2][0] += A2 * xv0; cacc[2][1] += A2 * xv1; cacc[2][2] += A2 * xv2; cacc[2][3] += A2 * xv3;
        cacc[3][0] += A3 * xv0; cacc[3][1] += A3 * xv1; cacc[3][2] += A3 * xv2; cacc[3][3] += A3 * xv3;
      }
      #pragma unroll
      for (int r = 0; r < 4; ++r) {
        short8 wvv;
        #pragma unroll
        for (int j = 0; j < 4; ++j) {
          wvv[2 * j]     = (short)f2bf(cacc[r][j][0] * inv);
          wvv[2 * j + 1] = (short)f2bf(cacc[r][j][1] * inv);
        }
        *(short8*)&aggs[t][(r << 6) + c0] = wvv;
      }
    }
    __syncthreads();

    // phase D: out[128][32] = pwb @ aggs^T via mfma 16x16x32 bf16
    f32x4 dacc[2][2];
    #pragma unroll
    for (int i = 0; i < 2; ++i)
      #pragma unroll
      for (int j = 0; j < 2; ++j) dacc[i][j] = (f32x4){0.f, 0.f, 0.f, 0.f};

    #pragma unroll
    for (int ks = 0; ks < 8; ++ks) {
      short8 b0 = *(const short8*)&aggs[lr][(ks << 5) + (lq << 3)];
      short8 b1 = *(const short8*)&aggs[16 + lr][(ks << 5) + (lq << 3)];
      dacc[0][0] = __builtin_amdgcn_mfma_f32_16x16x32_bf16(a0r[ks], b0, dacc[0][0], 0, 0, 0);
      dacc[0][1] = __builtin_amdgcn_mfma_f32_16x16x32_bf16(a0r[ks], b1, dacc[0][1], 0, 0, 0);
      dacc[1][0] = __builtin_amdgcn_mfma_f32_16x16x32_bf16(a1r[ks], b0, dacc[1][0], 0, 0, 0);
      dacc[1][1] = __builtin_amdgcn_mfma_f32_16x16x32_bf16(a1r[ks], b1, dacc[1][1], 0, 0, 0);
    }

    // epilogue: full 128B line per channel-row in one burst
    #pragma unroll
    for (int oi = 0; oi < 2; ++oi) {
      float4 pbv = oi ? pbv1 : pbv0;
      #pragma unroll
      for (int q = 0; q < 4; ++q) {
        int o = o0 + (oi << 4) + (lq << 2) + q;
        size_t base = (((size_t)b * COUT + o) << 14) + ((h0 + p) << 7) + w0;
        out[base + lr]      = dacc[oi][0][q] + pbv[q];
        out[base + 16 + lr] = dacc[oi][1][q] + pbv[q];
      }
    }
    if (p == 0) __syncthreads();   // protect aggs before next round's phase C
  }
}

extern "C" void kernel_launch(void* const* d_in, const int* in_sizes, int n_in,
                              void* d_out, int out_size, void* d_ws, size_t ws_size,
                              hipStream_t stream) {
  const float* x     = (const float*)d_in[0];
  const float* gw    = (const float*)d_in[1];
  const float* gb    = (const float*)d_in[2];
  const float* theta = (const float*)d_in[3];
  const float* rsu   = (const float*)d_in[4];
  const float* rss   = (const float*)d_in[5];
  const float* pw    = (const float*)d_in[6];
  const float* pb    = (const float*)d_in[7];
  float* outp = (float*)d_out;

  float* wkern = (float*)d_ws;                           // 64 floats
  unsigned short* pwb = (unsigned short*)(wkern + 64);   // 32768 bf16
  unsigned short* gwb = pwb + COUT * RR * CC;            // 1024 bf16 [16][64]

  k_pre<<<128, 256, 0, stream>>>(theta, rsu, rss, pw, gw, wkern, pwb, gwb);
  k_fused<<<BB * (HH / 2) * (WW / 32), 256, 0, stream>>>(x, gb, wkern, pwb, gwb, pb, outp);
}

// Round 11
// 51.103 us; speedup vs baseline: 1.9709x; 1.1596x over previous
//
#include <hip/hip_runtime.h>
#include <math.h>

#define CC 64
#define RR 4
#define HH 128
#define WW 128
#define BB 8
#define COUT 128
#define XST 72    // xsT row stride in ushorts (144B = 36 dw); XOR-swizzled blocks
#define ALS 44    // alp row stride in ushorts (88B, 8B-aligned)

typedef __attribute__((ext_vector_type(8))) short short8;
typedef __attribute__((ext_vector_type(4))) float f32x4;
typedef __attribute__((ext_vector_type(2))) float f32x2;

__device__ __forceinline__ unsigned short f2bf(float f) {
  unsigned u = __float_as_uint(f);
  u += 0x7fffu + ((u >> 16) & 1u);
  return (unsigned short)(u >> 16);
}
__device__ __forceinline__ float blo(unsigned u) { return __uint_as_float(u << 16); }
__device__ __forceinline__ float bhi(unsigned u) { return __uint_as_float(u & 0xffff0000u); }
// channel-block swizzle: partners 8-apart in sp get distinct banks
__device__ __forceinline__ int swzx(int cb, int sp) { return cb ^ ((sp >> 3) & 7); }
// aggs block swizzle: partners 8-apart in row get distinct banks
__device__ __forceinline__ int swza(int cb, int row) { return cb ^ ((row >> 3) & 3); }

// --- K0: kern table + pw -> bf16 + zero-padded gw -> bf16 [16][64]
__global__ __launch_bounds__(256) void k_pre(const float* __restrict__ theta,
                                             const float* __restrict__ rsu,
                                             const float* __restrict__ rss,
                                             const float* __restrict__ pw,
                                             const float* __restrict__ gw,
                                             float* __restrict__ wkern,
                                             unsigned short* __restrict__ pwb,
                                             unsigned short* __restrict__ gwb) {
  int i = blockIdx.x * 256 + threadIdx.x;
  if (i < COUT * RR * CC) pwb[i] = f2bf(pw[i]);
  if (blockIdx.x == 0 && threadIdx.x < RR * 9) {
    int t = threadIdx.x;
    int r = t / 9, s = t % 9;
    float dy = (float)(s / 3 - 1), dx = (float)(s % 3 - 1);
    float ct = cosf(theta[r]), st = sinf(theta[r]);
    float su = log1pf(expf(rsu[r])) + 1e-4f;
    float sv = log1pf(expf(rss[r])) + 1e-4f;
    float pu = ct * dx + st * dy;
    float ps = -st * dx + ct * dy;
    wkern[t] = expf(-(pu * pu) / (su * su) - (ps * ps) / (sv * sv));
  }
  if (blockIdx.x == 1) {
    #pragma unroll
    for (int k = 0; k < 4; ++k) {
      int j = k * 256 + threadIdx.x;     // 0..1023 over [16][64]
      gwb[j] = (j < RR * CC) ? f2bf(gw[j]) : (unsigned short)0;
    }
  }
}

// --- K1: fully fused, swizzled transposed x tile. 2 rows x 32 cols; 2048 blocks
__global__ __launch_bounds__(256, 3) void k_fused(const float* __restrict__ x,
                                                  const float* __restrict__ gb,
                                                  const float* __restrict__ wkern,
                                                  const unsigned short* __restrict__ pwb,
                                                  const unsigned short* __restrict__ gwb,
                                                  const float* __restrict__ pb,
                                                  float* __restrict__ out) {
  __shared__ unsigned short xsT[160][XST];   // bf16 x halo [sp=row*40+col][swz channel]
  __shared__ float mus[RR][4][40];           // mu halo (cols 3..36 valid)
  __shared__ unsigned short alp[64][ALS];    // raw bf16 alpha [px][s*4+r]
  __shared__ float rsum[RR][64];             // per-r raw-alpha sums
  __shared__ __align__(16) unsigned short aggs[32][264];  // bf16 agg, swz blocks

  int tid = threadIdx.x;
  int raw = blockIdx.x;
  int bid = (raw & 7) * 256 + (raw >> 3);    // XCD swizzle (2048 % 8 == 0)
  int b = bid >> 8;
  int rem = bid & 255;
  int h0 = (rem >> 2) << 1;                  // 64 h-tiles of 2 rows
  int w0 = (rem & 3) << 5;                   // 4 w-tiles of 32 cols

  int lane = tid & 63;
  int wv = tid >> 6;
  int lr = lane & 15, lq = lane >> 4;
  int o0 = wv << 5;

  // ---- A-fragments (GEMM) + mu A-fragments + bias preload
  short8 a0r[8], a1r[8];
  {
    const unsigned short* pA = pwb + ((o0 + lr) << 8) + (lq << 3);
    #pragma unroll
    for (int ks = 0; ks < 8; ++ks) {
      a0r[ks] = *(const short8*)(pA + (ks << 5));
      a1r[ks] = *(const short8*)(pA + 4096 + (ks << 5));
    }
  }
  short8 am0 = *(const short8*)(gwb + (lr << 6) + (lq << 3));
  short8 am1 = *(const short8*)(gwb + (lr << 6) + 32 + (lq << 3));
  float4 pbv0 = *(const float4*)&pb[o0 + (lq << 2)];
  float4 pbv1 = *(const float4*)&pb[o0 + 16 + (lq << 2)];
  float gb0 = gb[0], gb1 = gb[1], gb2 = gb[2], gb3 = gb[3];

  // ---- phase A: stage x halo transposed+swizzled; 640 4-channel items
  #pragma unroll
  for (int k = 0; k < 3; ++k) {
    int item = k * 256 + tid;                 // 0..639
    if (item < 640) {
      int c4 = item % 10;                     // f4 slot in row (0..9)
      int rest = item / 10;                   // 0..63
      int row = rest & 3, cquad = rest >> 2;  // 4 rows, 16 channel-quads
      int c = cquad << 2;
      int gcol = w0 - 4 + (c4 << 2);
      int grow = h0 - 1 + row;
      float4 v0 = make_float4(0.f,0.f,0.f,0.f), v1 = v0, v2 = v0, v3 = v0;
      if ((unsigned)gcol < WW && (unsigned)grow < HH) {
        const float* xp = x + (((size_t)b * CC + c) << 14) + (grow << 7) + gcol;
        v0 = *(const float4*)xp;
        v1 = *(const float4*)(xp + (1 << 14));
        v2 = *(const float4*)(xp + (2 << 14));
        v3 = *(const float4*)(xp + (3 << 14));
      }
      int spb = row * 40 + (c4 << 2);
      int cb = cquad >> 1, sub = (cquad & 1) << 2;
      float4 vv[4] = {v0, v1, v2, v3};
      #pragma unroll
      for (int j = 0; j < 4; ++j) {
        int sp = spb + j;
        ushort4 uv;
        uv.x = f2bf(vv[0].x); uv.y = f2bf(vv[1].x); uv.z = f2bf(vv[2].x); uv.w = f2bf(vv[3].x);
        // rotate: component j of each vv
        float f0 = (&vv[0].x)[j], f1 = (&vv[1].x)[j], f2v = (&vv[2].x)[j], f3 = (&vv[3].x)[j];
        uv.x = f2bf(f0); uv.y = f2bf(f1); uv.z = f2bf(f2v); uv.w = f2bf(f3);
        *(ushort4*)&xsT[sp][(swzx(cb, sp) << 3) + sub] = uv;
      }
    }
  }
  __syncthreads();

  // ---- phase Mu (MFMA): logits = gwb @ xsT-cols (swizzled b128 fragments)
  for (int j = wv; j < 9; j += 4) {
    int p = (j << 4) + lr;
    int pcl = p > 135 ? 135 : p;
    unsigned y = (unsigned)pcl / 34u;
    int cxo = pcl - (int)(y * 34u);
    int pos = (int)y * 40 + 3 + cxo;
    short8 b0 = *(const short8*)&xsT[pos][swzx(lq, pos) << 3];
    short8 b1 = *(const short8*)&xsT[pos][swzx(4 + lq, pos) << 3];
    f32x4 mac = (f32x4){0.f, 0.f, 0.f, 0.f};
    mac = __builtin_amdgcn_mfma_f32_16x16x32_bf16(am0, b0, mac, 0, 0, 0);
    mac = __builtin_amdgcn_mfma_f32_16x16x32_bf16(am1, b1, mac, 0, 0, 0);
    if (lq == 0 && p < 136) {
      int grow = h0 - 1 + (int)y, gcol = w0 - 1 + cxo;
      float lg0 = mac[0] + gb0, lg1 = mac[1] + gb1;
      float lg2 = mac[2] + gb2, lg3 = mac[3] + gb3;
      float m = fmaxf(fmaxf(lg0, lg1), fmaxf(lg2, lg3));
      float e0 = expf(lg0 - m), e1 = expf(lg1 - m);
      float e2 = expf(lg2 - m), e3 = expf(lg3 - m);
      float inv = 1.0f / (e0 + e1 + e2 + e3);
      if (!((unsigned)grow < HH && (unsigned)gcol < WW)) inv = 0.0f;  // zero-pad mu
      mus[0][y][3 + cxo] = e0 * inv;
      mus[1][y][3 + cxo] = e1 * inv;
      mus[2][y][3 + cxo] = e2 * inv;
      mus[3][y][3 + cxo] = e3 * inv;
    }
  }
  __syncthreads();

  // ---- phase B: raw alpha (bf16) per (px, r) from wkern table; write rsum
  {
    int t = tid & 63, r = tid >> 6;          // r wave-uniform -> wkern scalar loads
    int prow = t >> 5, pcol = t & 31;
    float mc = mus[r][prow + 1][pcol + 4];
    float sum = 0.f;
    #pragma unroll
    for (int s = 0; s < 9; ++s) {
      float av = mc * mus[r][prow + s / 3][pcol + 3 + s % 3] * wkern[r * 9 + s];
      alp[t][(s << 2) + r] = f2bf(av);
      sum += av;
    }
    rsum[r][t] = sum;
  }
  __syncthreads();

  // ---- rounds: 2 x (C: 32-px agg -> D: MFMA + full-line stores)
  #pragma unroll
  for (int p = 0; p < 2; ++p) {
    // phase C: 32 px x 8 c-groups of 8 channels; swizzled b128 per s
    {
      int t = tid & 31, cg = tid >> 5;
      int px = (p << 5) + t;
      float inv = 1.0f / fmaxf(rsum[0][px] + rsum[1][px] + rsum[2][px] + rsum[3][px], 1e-8f);

      uint2 ad[9];
      #pragma unroll
      for (int s = 0; s < 9; ++s) ad[s] = *(const uint2*)(&alp[px][s << 2]);

      f32x2 cacc[4][4];
      #pragma unroll
      for (int r = 0; r < 4; ++r)
        #pragma unroll
        for (int j = 0; j < 4; ++j) cacc[r][j] = (f32x2){0.f, 0.f};

      #pragma unroll
      for (int s = 0; s < 9; ++s) {
        int sp = (p + s / 3) * 40 + t + 3 + s % 3;
        uint4 ux = *(const uint4*)&xsT[sp][swzx(cg, sp) << 3];
        f32x2 xv0 = {blo(ux.x), bhi(ux.x)};
        f32x2 xv1 = {blo(ux.y), bhi(ux.y)};
        f32x2 xv2 = {blo(ux.z), bhi(ux.z)};
        f32x2 xv3 = {blo(ux.w), bhi(ux.w)};
        unsigned adx = ad[s].x, ady = ad[s].y;
        float af0 = blo(adx), af1 = bhi(adx), af2 = blo(ady), af3 = bhi(ady);
        f32x2 A0 = {af0, af0}, A1 = {af1, af1}, A2 = {af2, af2}, A3 = {af3, af3};
        cacc[0][0] += A0 * xv0; cacc[0][1] += A0 * xv1; cacc[0][2] += A0 * xv2; cacc[0][3] += A0 * xv3;
        cacc[1][0] += A1 * xv0; cacc[1][1] += A1 * xv1; cacc[1][2] += A1 * xv2; cacc[1][3] += A1 * xv3;
        cacc[2][0] += A2 * xv0; cacc[2][1] += A2 * xv1; cacc[2][2] += A2 * xv2; cacc[2][3] += A2 * xv3;
        cacc[3][0] += A3 * xv0; cacc[3][1] += A3 * xv1; cacc[3][2] += A3 * xv2; cacc[3][3] += A3 * xv3;
      }
      #pragma unroll
      for (int r = 0; r < 4; ++r) {
        short8 wvv;
        #pragma unroll
        for (int j = 0; j < 4; ++j) {
          wvv[2 * j]     = (short)f2bf(cacc[r][j][0] * inv);
          wvv[2 * j + 1] = (short)f2bf(cacc[r][j][1] * inv);
        }
        *(short8*)&aggs[t][swza((r << 3) + cg, t) << 3] = wvv;
      }
    }
    __syncthreads();

    // phase D: out[128][32] = pwb @ aggs^T via mfma 16x16x32 bf16
    f32x4 dacc[2][2];
    #pragma unroll
    for (int i = 0; i < 2; ++i)
      #pragma unroll
      for (int j = 0; j < 2; ++j) dacc[i][j] = (f32x4){0.f, 0.f, 0.f, 0.f};

    #pragma unroll
    for (int ks = 0; ks < 8; ++ks) {
      short8 b0 = *(const short8*)&aggs[lr][swza((ks << 2) + lq, lr) << 3];
      short8 b1 = *(const short8*)&aggs[16 + lr][swza((ks << 2) + lq, 16 + lr) << 3];
      dacc[0][0] = __builtin_amdgcn_mfma_f32_16x16x32_bf16(a0r[ks], b0, dacc[0][0], 0, 0, 0);
      dacc[0][1] = __builtin_amdgcn_mfma_f32_16x16x32_bf16(a0r[ks], b1, dacc[0][1], 0, 0, 0);
      dacc[1][0] = __builtin_amdgcn_mfma_f32_16x16x32_bf16(a1r[ks], b0, dacc[1][0], 0, 0, 0);
      dacc[1][1] = __builtin_amdgcn_mfma_f32_16x16x32_bf16(a1r[ks], b1, dacc[1][1], 0, 0, 0);
    }

    // epilogue: full 128B line per channel-row in one burst
    #pragma unroll
    for (int oi = 0; oi < 2; ++oi) {
      float4 pbv = oi ? pbv1 : pbv0;
      #pragma unroll
      for (int q = 0; q < 4; ++q) {
        int o = o0 + (oi << 4) + (lq << 2) + q;
        size_t base = (((size_t)b * COUT + o) << 14) + ((h0 + p) << 7) + w0;
        out[base + lr]      = dacc[oi][0][q] + pbv[q];
        out[base + 16 + lr] = dacc[oi][1][q] + pbv[q];
      }
    }
    if (p == 0) __syncthreads();   // protect aggs before next round's phase C
  }
}

extern "C" void kernel_launch(void* const* d_in, const int* in_sizes, int n_in,
                              void* d_out, int out_size, void* d_ws, size_t ws_size,
                              hipStream_t stream) {
  const float* x     = (const float*)d_in[0];
  const float* gw    = (const float*)d_in[1];
  const float* gb    = (const float*)d_in[2];
  const float* theta = (const float*)d_in[3];
  const float* rsu   = (const float*)d_in[4];
  const float* rss   = (const float*)d_in[5];
  const float* pw    = (const float*)d_in[6];
  const float* pb    = (const float*)d_in[7];
  float* outp = (float*)d_out;

  float* wkern = (float*)d_ws;                           // 64 floats
  unsigned short* pwb = (unsigned short*)(wkern + 64);   // 32768 bf16
  unsigned short* gwb = pwb + COUT * RR * CC;            // 1024 bf16 [16][64]

  k_pre<<<128, 256, 0, stream>>>(theta, rsu, rss, pw, gw, wkern, pwb, gwb);
  k_fused<<<BB * (HH / 2) * (WW / 32), 256, 0, stream>>>(x, gb, wkern, pwb, gwb, pb, outp);
}